// Round 1
// baseline (261.313 us; speedup 1.0000x reference)
//
#include <hip/hip_runtime.h>
#include <math.h>

#define NPTS 2000000
#define DIM 16
#define NCL 64
#define EPSF 1e-8f

// ws float layout:
//   [0,1024)    sums[64][16]
//   [1024,1088) counts[64]
//   [1088,2112) means[64][16]
//   [2112,2176) h2sums[64]
//   [2176]      inter_loss
//   [2177]      reg_loss
#define WS_SUMS   0
#define WS_CNT    1024
#define WS_MEANS  1088
#define WS_H2     2112
#define WS_INTER  2176
#define WS_REG    2177
#define WS_FLOATS 2178

// Pass 1: per-cluster feature sums + counts.
// 4 lanes per point; lane q handles dims [4q,4q+4).
__global__ void __launch_bounds__(256) k_sums(const float4* __restrict__ feat,
                                              const int* __restrict__ lab,
                                              float* __restrict__ ws) {
    __shared__ float s_sums[NCL * 17];
    __shared__ float s_cnt[NCL];
    for (int i = threadIdx.x; i < NCL * 17; i += 256) s_sums[i] = 0.f;
    for (int i = threadIdx.x; i < NCL; i += 256) s_cnt[i] = 0.f;
    __syncthreads();

    const int total = NPTS * 4;
    const int stride = gridDim.x * 256;
    for (int idx = blockIdx.x * 256 + threadIdx.x; idx < total; idx += stride) {
        int p = idx >> 2, q = idx & 3;
        int l = lab[p];
        float4 v = feat[idx];
        float* dst = &s_sums[l * 17 + q * 4];
        atomicAdd(dst + 0, v.x);
        atomicAdd(dst + 1, v.y);
        atomicAdd(dst + 2, v.z);
        atomicAdd(dst + 3, v.w);
        if (q == 0) atomicAdd(&s_cnt[l], 1.0f);
    }
    __syncthreads();

    for (int i = threadIdx.x; i < NCL * DIM; i += 256) {
        float v = s_sums[(i >> 4) * 17 + (i & 15)];
        if (v != 0.f) atomicAdd(&ws[WS_SUMS + i], v);
    }
    for (int i = threadIdx.x; i < NCL; i += 256) {
        float v = s_cnt[i];
        if (v != 0.f) atomicAdd(&ws[WS_CNT + i], v);
    }
}

// Tiny: means = sums/counts; inter-pair hinge; reg norm. One block, 256 thr.
__global__ void __launch_bounds__(256) k_means_inter(float* __restrict__ ws) {
    __shared__ float s_means[NCL * 17];
    __shared__ float red[8];
    int tid = threadIdx.x;

    for (int i = tid; i < NCL * DIM; i += 256) {
        float m = ws[WS_SUMS + i] / ws[WS_CNT + (i >> 4)];
        ws[WS_MEANS + i] = m;
        s_means[(i >> 4) * 17 + (i & 15)] = m;
    }
    __syncthreads();

    float inter = 0.f;
    for (int pr = tid; pr < NCL * NCL; pr += 256) {
        int i = pr >> 6, j = pr & 63;
        if (i != j) {
            float ss = 0.f;
#pragma unroll
            for (int k = 0; k < DIM; ++k) {
                float dv = s_means[i * 17 + k] - s_means[j * 17 + k] + EPSF;
                ss += dv * dv;
            }
            float h = fmaxf(3.0f - sqrtf(ss), 0.f);  // 2*INTER_MARGIN = 3.0
            inter += h * h;
        }
    }
    float reg = 0.f;
    if (tid < NCL) {
        float ss = 0.f;
#pragma unroll
        for (int k = 0; k < DIM; ++k) {
            float m = s_means[tid * 17 + k] + EPSF;
            ss += m * m;
        }
        reg = sqrtf(ss);
    }
#pragma unroll
    for (int m = 1; m < 64; m <<= 1) {
        inter += __shfl_xor(inter, m);
        reg += __shfl_xor(reg, m);
    }
    int wave = tid >> 6;
    if ((tid & 63) == 0) { red[wave] = inter; red[4 + wave] = reg; }
    __syncthreads();
    if (tid == 0) {
        float it = red[0] + red[1] + red[2] + red[3];
        float rg = red[4] + red[5] + red[6] + red[7];
        ws[WS_INTER] = it / (float)(NCL * (NCL - 1));
        ws[WS_REG] = rg / (float)NCL;
    }
}

// Pass 2: per-cluster sum of hinge^2 of (||x - mean[label] + eps|| - 0.5).
__global__ void __launch_bounds__(256) k_intra(const float4* __restrict__ feat,
                                               const int* __restrict__ lab,
                                               float* __restrict__ ws) {
    __shared__ float s_means[NCL * 17];
    __shared__ float s_h2[NCL];
    for (int i = threadIdx.x; i < NCL * DIM; i += 256)
        s_means[(i >> 4) * 17 + (i & 15)] = ws[WS_MEANS + i];
    for (int i = threadIdx.x; i < NCL; i += 256) s_h2[i] = 0.f;
    __syncthreads();

    const int total = NPTS * 4;
    const int stride = gridDim.x * 256;
    for (int idx = blockIdx.x * 256 + threadIdx.x; idx < total; idx += stride) {
        int p = idx >> 2, q = idx & 3;
        int l = lab[p];
        float4 v = feat[idx];
        const float* m = &s_means[l * 17 + q * 4];
        float d0 = v.x - m[0] + EPSF;
        float d1 = v.y - m[1] + EPSF;
        float d2 = v.z - m[2] + EPSF;
        float d3 = v.w - m[3] + EPSF;
        float ss = d0 * d0 + d1 * d1 + d2 * d2 + d3 * d3;
        ss += __shfl_xor(ss, 1);
        ss += __shfl_xor(ss, 2);
        if (q == 0) {
            float h = fmaxf(sqrtf(ss) - 0.5f, 0.f);
            atomicAdd(&s_h2[l], h * h);
        }
    }
    __syncthreads();
    for (int i = threadIdx.x; i < NCL; i += 256) {
        float v = s_h2[i];
        if (v != 0.f) atomicAdd(&ws[WS_H2 + i], v);
    }
}

// Final combine: intra = mean_c(h2sum_c / count_c); loss scalar.
__global__ void k_final(const float* __restrict__ ws, float* __restrict__ out) {
    int t = threadIdx.x;  // 64 threads
    float v = ws[WS_H2 + t] / ws[WS_CNT + t];
#pragma unroll
    for (int m = 1; m < 64; m <<= 1) v += __shfl_xor(v, m);
    if (t == 0) {
        float intra = v / (float)NCL;
        out[0] = intra + ws[WS_INTER] + 0.001f * ws[WS_REG];
    }
}

extern "C" void kernel_launch(void* const* d_in, const int* in_sizes, int n_in,
                              void* d_out, int out_size, void* d_ws, size_t ws_size,
                              hipStream_t stream) {
    const float4* feat = (const float4*)d_in[0];
    const int* lab = (const int*)d_in[1];
    float* ws = (float*)d_ws;
    float* out = (float*)d_out;

    hipMemsetAsync(d_ws, 0, WS_FLOATS * sizeof(float), stream);

    const int blocks = 2048;
    k_sums<<<blocks, 256, 0, stream>>>(feat, lab, ws);
    k_means_inter<<<1, 256, 0, stream>>>(ws);
    k_intra<<<blocks, 256, 0, stream>>>(feat, lab, ws);
    k_final<<<1, 64, 0, stream>>>(ws, out);
}